// Round 1
// baseline (734.783 us; speedup 1.0000x reference)
//
#include <hip/hip_runtime.h>

// out[b,z] = sum_ij C[z,i,j] x[b,i] y[b,j],  B=256, D=128, Z=8256
// Restructured: for each i: out[:, zt] += diag(x[:,i]) * (Y_bf16 @ C[zt,i,:]^T)
// Y (256x128) lives in registers as MFMA A-fragments for the whole kernel.
// C (541 MB) is streamed exactly once: quantum = (z-tile of 32, i).

typedef __bf16 bf16x8 __attribute__((ext_vector_type(8)));
typedef float floatx4 __attribute__((ext_vector_type(4)));

#define TPB 256
#define GRID 512
#define NQ 33024   // 258 z-tiles * 128 i

__global__ __launch_bounds__(TPB, 2)
void rtp_mfma_kernel(const float* __restrict__ xg,
                     const float* __restrict__ yg,
                     const float* __restrict__ Cg,
                     float* __restrict__ out)
{
    // C-tile: 32 z-rows x 128 j, bf16, +8 pad => row stride 272 B (17*16 B):
    // b128 reads land 2-way bank-aliased only (free).
    __shared__ __align__(16) __bf16 ct[2][32][136];
    __shared__ float xcol[2][256];

    const int tid   = threadIdx.x;
    const int wave  = tid >> 6;
    const int lane  = tid & 63;
    const int l15   = lane & 15;
    const int quad  = lane >> 4;
    const int wbase = wave << 6;

    const floatx4 z4 = {0.f, 0.f, 0.f, 0.f};

    // ---- Y fragments, resident all kernel: yf[mb][w], A[m=l&15][k=quad*8+j] ----
    bf16x8 yf[4][4];
#pragma unroll
    for (int mb = 0; mb < 4; ++mb) {
        const float* yrow = yg + (wbase + mb * 16 + l15) * 128;
#pragma unroll
        for (int w = 0; w < 4; ++w) {
            const float4 f0 = *(const float4*)(yrow + w * 32 + quad * 8);
            const float4 f1 = *(const float4*)(yrow + w * 32 + quad * 8 + 4);
            bf16x8 v;
            v[0] = (__bf16)f0.x; v[1] = (__bf16)f0.y;
            v[2] = (__bf16)f0.z; v[3] = (__bf16)f0.w;
            v[4] = (__bf16)f1.x; v[5] = (__bf16)f1.y;
            v[6] = (__bf16)f1.z; v[7] = (__bf16)f1.w;
            yf[mb][w] = v;
        }
    }

    // staging coords: thread -> (z-row, 16-float j-chunk)
    const int sz = tid >> 3;         // 0..31
    const int sj = (tid & 7) << 4;   // 0..112

    // flat quantum range: WG gets 64 or 65 of 33024 quanta (contiguous)
    int q        = ((int)blockIdx.x * 129) >> 1;
    const int q1 = (((int)blockIdx.x + 1) * 129) >> 1;

    float4 pv0, pv1, pv2, pv3;  // prefetched C tile slice (16 fp32)
    float  pxv;                 // prefetched x value

    while (q < q1) {
        const int zt   = q >> 7;
        const int i0   = q & 127;
        const int qrem = q1 - q;
        const int ilen = (128 - i0) < qrem ? (128 - i0) : qrem;

        const float* crow = Cg + ((size_t)(zt * 32 + sz) << 14) + sj;

        auto loadtile = [&](int i) {
            const float4* s = (const float4*)(crow + (size_t)i * 128);
            pv0 = s[0]; pv1 = s[1]; pv2 = s[2]; pv3 = s[3];
            pxv = xg[tid * 128 + i];
        };
        auto commit = [&](int cb) {
            bf16x8 p0, p1;
            p0[0] = (__bf16)pv0.x; p0[1] = (__bf16)pv0.y;
            p0[2] = (__bf16)pv0.z; p0[3] = (__bf16)pv0.w;
            p0[4] = (__bf16)pv1.x; p0[5] = (__bf16)pv1.y;
            p0[6] = (__bf16)pv1.z; p0[7] = (__bf16)pv1.w;
            p1[0] = (__bf16)pv2.x; p1[1] = (__bf16)pv2.y;
            p1[2] = (__bf16)pv2.z; p1[3] = (__bf16)pv2.w;
            p1[4] = (__bf16)pv3.x; p1[5] = (__bf16)pv3.y;
            p1[6] = (__bf16)pv3.z; p1[7] = (__bf16)pv3.w;
            *(bf16x8*)&ct[cb][sz][sj]     = p0;
            *(bf16x8*)&ct[cb][sz][sj + 8] = p1;
            xcol[cb][tid] = pxv;
        };

        floatx4 acc[4][2];
#pragma unroll
        for (int mb = 0; mb < 4; ++mb) { acc[mb][0] = z4; acc[mb][1] = z4; }

        loadtile(i0);
        __syncthreads();          // previous run fully done with LDS
        commit(0);
        if (ilen > 1) loadtile(i0 + 1);
        __syncthreads();

        for (int t = 0; t < ilen; ++t) {
            const int buf = t & 1;
            if (t + 1 < ilen) {
                commit((t + 1) & 1);              // tile t+1 -> other buffer
                if (t + 2 < ilen) loadtile(i0 + t + 2);  // global prefetch in flight over MFMA
            }

            // x values for this i: rows quad*4+r within each 16-row block
            floatx4 xv[4];
#pragma unroll
            for (int mb = 0; mb < 4; ++mb)
                xv[mb] = *(const floatx4*)&xcol[buf][wbase + mb * 16 + quad * 4];

            floatx4 S[4][2];
#pragma unroll
            for (int mb = 0; mb < 4; ++mb) { S[mb][0] = z4; S[mb][1] = z4; }

#pragma unroll
            for (int w = 0; w < 4; ++w) {
                const bf16x8 b0 = *(const bf16x8*)&ct[buf][l15][w * 32 + quad * 8];
                const bf16x8 b1 = *(const bf16x8*)&ct[buf][l15 + 16][w * 32 + quad * 8];
#pragma unroll
                for (int mb = 0; mb < 4; ++mb) {
                    S[mb][0] = __builtin_amdgcn_mfma_f32_16x16x32_bf16(yf[mb][w], b0, S[mb][0], 0, 0, 0);
                    S[mb][1] = __builtin_amdgcn_mfma_f32_16x16x32_bf16(yf[mb][w], b1, S[mb][1], 0, 0, 0);
                }
            }
            // fold x[b,i] into the accumulator (C/D layout: row = quad*4+r)
#pragma unroll
            for (int mb = 0; mb < 4; ++mb) {
                acc[mb][0] += xv[mb] * S[mb][0];
                acc[mb][1] += xv[mb] * S[mb][1];
            }
            __syncthreads();
        }

        // epilogue: accumulate partial z-tile into out
#pragma unroll
        for (int mb = 0; mb < 4; ++mb) {
            const int brow = wbase + mb * 16 + quad * 4;
#pragma unroll
            for (int nb = 0; nb < 2; ++nb) {
                const int zc = zt * 32 + nb * 16 + l15;
                float* o = out + (size_t)brow * 8256 + zc;
                atomicAdd(o,            acc[mb][nb][0]);
                atomicAdd(o + 8256,     acc[mb][nb][1]);
                atomicAdd(o + 16512,    acc[mb][nb][2]);
                atomicAdd(o + 24768,    acc[mb][nb][3]);
            }
        }
        q += ilen;
    }
}

extern "C" void kernel_launch(void* const* d_in, const int* in_sizes, int n_in,
                              void* d_out, int out_size, void* d_ws, size_t ws_size,
                              hipStream_t stream) {
    (void)in_sizes; (void)n_in; (void)d_ws; (void)ws_size;
    const float* x = (const float*)d_in[0];
    const float* y = (const float*)d_in[1];
    const float* C = (const float*)d_in[2];
    float* out = (float*)d_out;
    hipMemsetAsync(out, 0, (size_t)out_size * sizeof(float), stream);
    rtp_mfma_kernel<<<GRID, TPB, 0, stream>>>(x, y, C, out);
}